// Round 4
// baseline (262.101 us; speedup 1.0000x reference)
//
#include <hip/hip_runtime.h>
#include <math.h>

// Problem constants (match reference)
#define B_    8192
#define F_    64
#define V_    1000
#define E_    64
#define T_    2
#define NTOK_ 16
#define G_    4
#define D_    256
#define K_    128   // T*E
#define LN_EPS 1e-5f

#define R_    4     // batch rows per block
#define XSP   136   // xs row stride in bf16 (128 + 8 pad)

#define EB_ELEMS (T_*F_*V_*E_)   // 8,192,000
#define MB_ELEMS (T_*F_*E_)      // 8,192
#define WB_ELEMS (D_*K_)         // 32,768

typedef __attribute__((ext_vector_type(8))) short  frag_ab;  // 8 bf16 = 4 VGPRs
typedef __attribute__((ext_vector_type(4))) float  frag_cd;  // 4 fp32 acc

template<bool BT> struct GVec;
template<> struct GVec<true>  { using T = uint2;  };   // 4 bf16
template<> struct GVec<false> { using T = float4; };   // 4 fp32

static __device__ __forceinline__ unsigned short f2bf(float f) {
    unsigned int u = __float_as_uint(f);
    u += 0x7FFFu + ((u >> 16) & 1u);
    return (unsigned short)(u >> 16);
}
static __device__ __forceinline__ unsigned int pk2(float a, float b) {
    return (unsigned int)f2bf(a) | ((unsigned int)f2bf(b) << 16);
}
static __device__ __forceinline__ void g2f(uint2 v, float& a, float& b, float& c, float& d) {
    a = __uint_as_float(v.x << 16);
    b = __uint_as_float(v.x & 0xFFFF0000u);
    c = __uint_as_float(v.y << 16);
    d = __uint_as_float(v.y & 0xFFFF0000u);
}
static __device__ __forceinline__ void g2f(float4 v, float& a, float& b, float& c, float& d) {
    a = v.x; b = v.y; c = v.z; d = v.w;
}

// ---- prologue kernels: fp32 -> bf16 staging in workspace ----
__global__ __launch_bounds__(256) void convert_w_kernel(const float* __restrict__ W,
                                                        unsigned int* __restrict__ Wb_packed) {
    const int i = blockIdx.x * 256 + threadIdx.x;   // one uint = 2 bf16
    if (i < WB_ELEMS / 2) {
        const float2 v = *(const float2*)(W + (size_t)i * 2);
        Wb_packed[i] = pk2(v.x, v.y);
    }
}

__global__ __launch_bounds__(256) void convert_tbl_kernel(const float* __restrict__ emb,
                                                          const float* __restrict__ miss,
                                                          unsigned int* __restrict__ ebp,
                                                          unsigned int* __restrict__ mbp) {
    const int i = blockIdx.x * 256 + threadIdx.x;   // one thread = 4 floats
    const int neb = EB_ELEMS / 4;
    if (i < neb) {
        const float4 v = *(const float4*)(emb + (size_t)i * 4);
        ebp[2 * i]     = pk2(v.x, v.y);
        ebp[2 * i + 1] = pk2(v.z, v.w);
    } else if (i < neb + MB_ELEMS / 4) {
        const int j = i - neb;
        const float4 v = *(const float4*)(miss + (size_t)j * 4);
        mbp[2 * j]     = pk2(v.x, v.y);
        mbp[2 * j + 1] = pk2(v.z, v.w);
    }
}

// One block per R_=4 batch rows. 256 threads = 4 waves.
// Init: all rows' soff/mask in one parallel step; W frags + bias/gamma/beta +
//       row-invariant missing-emb values resident in registers.
// Pipeline per row: prefetch next row's gathers (registers, in flight across
// the current row's pack/MFMA/LN), pack -> xs[double buffer] -> MFMA with
// register-resident W -> register LN -> direct store.
template<bool BT, int MINW>
__global__ __launch_bounds__(256, MINW) void fused_tokenizer_kernel(
    const int*   __restrict__ int_feats,     // (B, F)
    const int*   __restrict__ missing_mask,  // (B, F)
    const int*   __restrict__ group_idx,     // (NTOK, G)
    const float* __restrict__ embf,          // (T, F, V, E) fp32 (fallback)
    const float* __restrict__ missf,         // (T, F, E) fp32 (fallback)
    const unsigned short* __restrict__ embb, // bf16 staged
    const unsigned short* __restrict__ missb,// bf16 staged
    const unsigned short* __restrict__ Wb,   // (D, K) bf16
    const float* __restrict__ bias,          // (D,)
    const float* __restrict__ gamma,         // (D,)
    const float* __restrict__ beta,          // (D,)
    float*       __restrict__ out)           // (B, NTOK, D)
{
    using VT = typename GVec<BT>::T;

    __shared__ unsigned short xs[2][NTOK_][XSP];   // 8.7 KB double buffer
    __shared__ unsigned int   soff[R_][F_];        // element offset | (mask<<31)
    __shared__ int            sg[F_];
    __shared__ float          part_s [4][NTOK_];
    __shared__ float          part_ss[4][NTOK_];

    const int tid  = threadIdx.x;
    const int lane = tid & 63;
    const int wave = tid >> 6;
    const int mA   = lane & 15;
    const int q    = lane >> 4;
    const int r0   = blockIdx.x * R_;

    // ---- init: all R_ rows' indices in one parallel step (4 rows x 64 f) ----
    {
        const int rr = tid >> 6, f = tid & 63;
        const int id = int_feats[(r0 + rr) * F_ + f];
        const unsigned int mk = (unsigned int)missing_mask[(r0 + rr) * F_ + f];
        soff[rr][f] = (unsigned int)((f * V_ + id) * E_) | (mk << 31);
        if (tid < F_) sg[tid] = group_idx[tid];
    }

    // ---- resident W fragments + per-column constants (once per block) ----
    frag_ab wfr[4][4];
    float bias_r[4], gm_r[4], bt_r[4];
#pragma unroll
    for (int t = 0; t < 4; ++t) {
        const int nrow = wave * 64 + t * 16 + mA;
        const unsigned short* wp = Wb + (size_t)nrow * K_ + 8 * q;
#pragma unroll
        for (int s = 0; s < 4; ++s) wfr[t][s] = *(const frag_ab*)(wp + 32 * s);
        bias_r[t] = bias[nrow];
        gm_r[t]   = gamma[nrow];
        bt_r[t]   = beta[nrow];
    }

    __syncthreads();   // soff/sg ready

    // ---- row-invariant per-thread geometry + missing-emb values (once) ----
    // chunk i: c = i*256+tid ; n=c>>5 ; r4=c&31 ; tt=r4>>4 ; e=(r4&15)*4
    VT  mval[2][G_];
    int fidx[2][G_];
#pragma unroll
    for (int i = 0; i < 2; ++i) {
        const int c = i * 256 + tid, n = c >> 5, r4 = c & 31, tt = r4 >> 4, e = (r4 & 15) * 4;
#pragma unroll
        for (int g = 0; g < G_; ++g) {
            const int f = sg[n * G_ + g];
            fidx[i][g] = f;
            const size_t mo = (size_t)(tt * F_ + f) * E_ + e;
            if constexpr (BT) mval[i][g] = *(const uint2*)(missb + mo);
            else              mval[i][g] = *(const float4*)(missf + mo);
        }
    }

    auto gather_issue = [&](int rr, VT (&gbuf)[2][G_]) {
#pragma unroll
        for (int i = 0; i < 2; ++i) {
            const int c = i * 256 + tid, r4 = c & 31, tt = r4 >> 4, e = (r4 & 15) * 4;
            const size_t tb = (size_t)tt * (F_ * V_ * E_) + e;
#pragma unroll
            for (int g = 0; g < G_; ++g) {
                const unsigned int so = soff[rr][fidx[i][g]] & 0x7FFFFFFFu;
                if constexpr (BT) gbuf[i][g] = *(const uint2*)(embb + tb + so);
                else              gbuf[i][g] = *(const float4*)(embf + tb + so);
            }
        }
    };

    auto pack_write = [&](int rr, unsigned short (&dst)[NTOK_][XSP], VT (&gbuf)[2][G_]) {
#pragma unroll
        for (int i = 0; i < 2; ++i) {
            const int c = i * 256 + tid, n = c >> 5, r4 = c & 31;
            float ax = 0.f, ay = 0.f, az = 0.f, aw = 0.f;
#pragma unroll
            for (int g = 0; g < G_; ++g) {
                float vx, vy, vz, vw, mx, my, mz, mw;
                g2f(gbuf[i][g], vx, vy, vz, vw);
                g2f(mval[i][g], mx, my, mz, mw);
                const float mf = (soff[rr][fidx[i][g]] >> 31) ? 1.f : 0.f;
                ax += vx + mf * mx;
                ay += vy + mf * my;
                az += vz + mf * mz;
                aw += vw + mf * mw;
            }
            *(uint2*)(&dst[n][r4 * 4]) =
                make_uint2(pk2(0.25f * ax, 0.25f * ay), pk2(0.25f * az, 0.25f * aw));
        }
    };

    // ---- software-pipelined row loop ----
    VT g0[2][G_], g1[2][G_];
    gather_issue(0, g0);

#pragma unroll
    for (int r = 0; r < R_; ++r) {
        if (r + 1 < R_) gather_issue(r + 1, g1);   // in flight across this row

        pack_write(r, xs[r & 1], g0);
        __syncthreads();   // barrier A: xs[r&1] ready

        frag_ab a[4];
#pragma unroll
        for (int s = 0; s < 4; ++s)
            a[s] = *(const frag_ab*)(&xs[r & 1][mA][32 * s + 8 * q]);

        float hv[4][4];
        float ps[4]  = {0.f, 0.f, 0.f, 0.f};
        float pss[4] = {0.f, 0.f, 0.f, 0.f};
#pragma unroll
        for (int t = 0; t < 4; ++t) {
            frag_cd acc = {0.f, 0.f, 0.f, 0.f};
#pragma unroll
            for (int s = 0; s < 4; ++s)
                acc = __builtin_amdgcn_mfma_f32_16x16x32_bf16(a[s], wfr[t][s], acc, 0, 0, 0);
#pragma unroll
            for (int reg = 0; reg < 4; ++reg) {
                const float z = acc[reg] + bias_r[t];
                const float h = z / (1.f + __expf(-z));   // silu
                hv[t][reg] = h;
                ps[reg]  += h;
                pss[reg] += h * h;
            }
        }

#pragma unroll
        for (int off = 1; off < 16; off <<= 1) {
#pragma unroll
            for (int reg = 0; reg < 4; ++reg) {
                ps[reg]  += __shfl_xor(ps[reg],  off, 64);
                pss[reg] += __shfl_xor(pss[reg], off, 64);
            }
        }
        if (mA == 0) {
            *(float4*)(&part_s [wave][q * 4]) = make_float4(ps[0],  ps[1],  ps[2],  ps[3]);
            *(float4*)(&part_ss[wave][q * 4]) = make_float4(pss[0], pss[1], pss[2], pss[3]);
        }
        __syncthreads();   // barrier B: partials ready

        const float4 S0 = *(const float4*)(&part_s [0][q * 4]);
        const float4 S1 = *(const float4*)(&part_s [1][q * 4]);
        const float4 S2 = *(const float4*)(&part_s [2][q * 4]);
        const float4 S3 = *(const float4*)(&part_s [3][q * 4]);
        const float4 T0 = *(const float4*)(&part_ss[0][q * 4]);
        const float4 T1 = *(const float4*)(&part_ss[1][q * 4]);
        const float4 T2 = *(const float4*)(&part_ss[2][q * 4]);
        const float4 T3 = *(const float4*)(&part_ss[3][q * 4]);

        float mu[4], rs[4];
        {
            const float s[4]  = {S0.x + S1.x + S2.x + S3.x, S0.y + S1.y + S2.y + S3.y,
                                 S0.z + S1.z + S2.z + S3.z, S0.w + S1.w + S2.w + S3.w};
            const float ss[4] = {T0.x + T1.x + T2.x + T3.x, T0.y + T1.y + T2.y + T3.y,
                                 T0.z + T1.z + T2.z + T3.z, T0.w + T1.w + T2.w + T3.w};
#pragma unroll
            for (int reg = 0; reg < 4; ++reg) {
                mu[reg] = s[reg] * (1.f / D_);
                const float var = ss[reg] * (1.f / D_) - mu[reg] * mu[reg];
                rs[reg] = rsqrtf(var + LN_EPS);
            }
        }

        const size_t obase = (size_t)(r0 + r) * (NTOK_ * D_);
#pragma unroll
        for (int t = 0; t < 4; ++t) {
            const int col = wave * 64 + t * 16 + mA;
            float* op = out + obase + col;
#pragma unroll
            for (int reg = 0; reg < 4; ++reg)
                op[(size_t)(q * 4 + reg) * D_] =
                    (hv[t][reg] - mu[reg]) * rs[reg] * gm_r[t] + bt_r[t];
        }

        // rotate prefetch registers
#pragma unroll
        for (int i = 0; i < 2; ++i)
#pragma unroll
            for (int g = 0; g < G_; ++g) g0[i][g] = g1[i][g];
    }
}

extern "C" void kernel_launch(void* const* d_in, const int* in_sizes, int n_in,
                              void* d_out, int out_size, void* d_ws, size_t ws_size,
                              hipStream_t stream) {
    const int*   int_feats    = (const int*)  d_in[0];
    const int*   missing_mask = (const int*)  d_in[1];
    const int*   group_idx    = (const int*)  d_in[2];
    const float* emb_tables   = (const float*)d_in[3];
    const float* missing_emb  = (const float*)d_in[4];
    const float* W            = (const float*)d_in[5];
    const float* bias         = (const float*)d_in[6];
    const float* gamma        = (const float*)d_in[7];
    const float* beta         = (const float*)d_in[8];
    float* out = (float*)d_out;

    unsigned short* Wb = (unsigned short*)d_ws;   // 64 KB bf16 W
    convert_w_kernel<<<(WB_ELEMS / 2 + 255) / 256, 256, 0, stream>>>(W, (unsigned int*)Wb);

    const size_t need = 2ull * (WB_ELEMS + MB_ELEMS + EB_ELEMS);   // ~16.5 MB
    if (ws_size >= need) {
        unsigned short* Mb = Wb + WB_ELEMS;
        unsigned short* Eb = Mb + MB_ELEMS;
        const int nch = (EB_ELEMS + MB_ELEMS) / 4;
        convert_tbl_kernel<<<(nch + 255) / 256, 256, 0, stream>>>(
            emb_tables, missing_emb, (unsigned int*)Eb, (unsigned int*)Mb);
        fused_tokenizer_kernel<true, 3><<<B_ / R_, 256, 0, stream>>>(
            int_feats, missing_mask, group_idx, nullptr, nullptr, Eb, Mb,
            Wb, bias, gamma, beta, out);
    } else {
        fused_tokenizer_kernel<false, 2><<<B_ / R_, 256, 0, stream>>>(
            int_feats, missing_mask, group_idx, emb_tables, missing_emb, nullptr, nullptr,
            Wb, bias, gamma, beta, out);
    }
}

// Round 5
// 245.126 us; speedup vs baseline: 1.0693x; 1.0693x over previous
//
#include <hip/hip_runtime.h>
#include <math.h>

// Problem constants (match reference)
#define B_    8192
#define F_    64
#define V_    1000
#define E_    64
#define T_    2
#define NTOK_ 16
#define G_    4
#define D_    256
#define K_    128   // T*E
#define LN_EPS 1e-5f

#define XSP   136   // xs row stride in bf16 (128 + 8 pad)

#define EB_ELEMS (T_*F_*V_*E_)   // 8,192,000
#define MB_ELEMS (T_*F_*E_)      // 8,192
#define WB_ELEMS (D_*K_)         // 32,768

typedef __attribute__((ext_vector_type(8))) short  frag_ab;  // 8 bf16 = 4 VGPRs
typedef __attribute__((ext_vector_type(4))) float  frag_cd;  // 4 fp32 acc

template<bool BT> struct GVec;
template<> struct GVec<true>  { using T = uint2;  };   // 4 bf16
template<> struct GVec<false> { using T = float4; };   // 4 fp32

static __device__ __forceinline__ unsigned short f2bf(float f) {
    unsigned int u = __float_as_uint(f);
    u += 0x7FFFu + ((u >> 16) & 1u);
    return (unsigned short)(u >> 16);
}
static __device__ __forceinline__ unsigned int pk2(float a, float b) {
    return (unsigned int)f2bf(a) | ((unsigned int)f2bf(b) << 16);
}
static __device__ __forceinline__ void g2f(uint2 v, float& a, float& b, float& c, float& d) {
    a = __uint_as_float(v.x << 16);
    b = __uint_as_float(v.x & 0xFFFF0000u);
    c = __uint_as_float(v.y << 16);
    d = __uint_as_float(v.y & 0xFFFF0000u);
}
static __device__ __forceinline__ void g2f(float4 v, float& a, float& b, float& c, float& d) {
    a = v.x; b = v.y; c = v.z; d = v.w;
}

// ---- prologue kernels: fp32 -> bf16 staging in workspace ----
__global__ __launch_bounds__(256) void convert_w_kernel(const float* __restrict__ W,
                                                        unsigned int* __restrict__ Wb_packed) {
    const int i = blockIdx.x * 256 + threadIdx.x;   // one uint = 2 bf16
    if (i < WB_ELEMS / 2) {
        const float2 v = *(const float2*)(W + (size_t)i * 2);
        Wb_packed[i] = pk2(v.x, v.y);
    }
}

__global__ __launch_bounds__(256) void convert_tbl_kernel(const float* __restrict__ emb,
                                                          const float* __restrict__ miss,
                                                          uint2* __restrict__ ebp,
                                                          uint2* __restrict__ mbp) {
    const int i = blockIdx.x * 256 + threadIdx.x;   // one thread = 4 floats -> uint2
    const int neb = EB_ELEMS / 4;
    if (i < neb) {
        const float4 v = *(const float4*)(emb + (size_t)i * 4);
        ebp[i] = make_uint2(pk2(v.x, v.y), pk2(v.z, v.w));
    } else if (i < neb + MB_ELEMS / 4) {
        const int j = i - neb;
        const float4 v = *(const float4*)(miss + (size_t)j * 4);
        mbp[j] = make_uint2(pk2(v.x, v.y), pk2(v.z, v.w));
    }
}

// One block per batch row. 256 threads = 4 waves.
// Phase 1: issue ALL 16 gathers (8 table + 8 missing) up front into registers,
//          then consume -> xs[16][128] bf16 in LDS.
// Phase 2: MFMA 16x16x32 bf16, W streamed from L2 (no register residency).
// Phase 3: register LayerNorm via 16-lane butterfly + tiny partial buffer.
template<bool BT, int MINW>
__global__ __launch_bounds__(256, MINW) void fused_tokenizer_kernel(
    const int*   __restrict__ int_feats,     // (B, F)
    const int*   __restrict__ missing_mask,  // (B, F)
    const int*   __restrict__ group_idx,     // (NTOK, G)
    const float* __restrict__ embf,          // (T, F, V, E) fp32 (fallback)
    const float* __restrict__ missf,         // (T, F, E) fp32 (fallback)
    const unsigned short* __restrict__ embb, // bf16 staged table
    const unsigned short* __restrict__ missb,// bf16 staged missing
    const unsigned short* __restrict__ Wb,   // (D, K) bf16
    const float* __restrict__ bias,          // (D,)
    const float* __restrict__ gamma,         // (D,)
    const float* __restrict__ beta,          // (D,)
    float*       __restrict__ out)           // (B, NTOK, D)
{
    using VT = typename GVec<BT>::T;

    __shared__ unsigned short xs[NTOK_][XSP];   // 4.3 KB
    __shared__ unsigned int   soff[F_];         // (f*V+id)*E | (mask<<31)
    __shared__ int            sg[F_];
    __shared__ float          part_s [4][NTOK_];
    __shared__ float          part_ss[4][NTOK_];

    const int tid  = threadIdx.x;
    const int b    = blockIdx.x;
    const int lane = tid & 63;
    const int wave = tid >> 6;
    const int mA   = lane & 15;
    const int q    = lane >> 4;

    if (tid < F_) {
        const int id = int_feats[b * F_ + tid];
        const unsigned int mk = (unsigned int)missing_mask[b * F_ + tid];
        soff[tid] = (unsigned int)((tid * V_ + id) * E_) | (mk << 31);
        sg[tid]   = group_idx[tid];   // NTOK*G == F == 64
    }
    __syncthreads();

    // ---- Phase 1a: issue all 16 independent loads ----
    // chunk i: c = i*256+tid ; n=c>>5 ; r4=c&31 ; tt=r4>>4 ; e=(r4&15)*4
    VT    gv[2][G_], mv[2][G_];
    float msk[2][G_];
#pragma unroll
    for (int i = 0; i < 2; ++i) {
        const int c = i * 256 + tid, n = c >> 5, r4 = c & 31, tt = r4 >> 4, e = (r4 & 15) * 4;
        const unsigned int tb = (unsigned int)(tt * (F_ * V_ * E_)) + e;
        const unsigned int mb = (unsigned int)(tt * (F_ * E_)) + e;
#pragma unroll
        for (int g = 0; g < G_; ++g) {
            const int f = sg[n * G_ + g];
            const unsigned int so = soff[f];
            msk[i][g] = (so >> 31) ? 1.f : 0.f;
            const unsigned int eo = tb + (so & 0x7FFFFFFFu);
            const unsigned int mo = mb + (unsigned int)(f * E_);
            if constexpr (BT) {
                gv[i][g] = *(const uint2*)(embb + eo);
                mv[i][g] = *(const uint2*)(missb + mo);
            } else {
                gv[i][g] = *(const float4*)(embf + eo);
                mv[i][g] = *(const float4*)(missf + mo);
            }
        }
    }

    // ---- Phase 1b: consume, pool, pack ----
#pragma unroll
    for (int i = 0; i < 2; ++i) {
        const int c = i * 256 + tid, n = c >> 5, r4 = c & 31;
        float ax = 0.f, ay = 0.f, az = 0.f, aw = 0.f;
#pragma unroll
        for (int g = 0; g < G_; ++g) {
            float vx, vy, vz, vw, mx, my, mz, mw;
            g2f(gv[i][g], vx, vy, vz, vw);
            g2f(mv[i][g], mx, my, mz, mw);
            const float m = msk[i][g];
            ax += vx + m * mx;
            ay += vy + m * my;
            az += vz + m * mz;
            aw += vw + m * mw;
        }
        *(uint2*)(&xs[n][r4 * 4]) =
            make_uint2(pk2(0.25f * ax, 0.25f * ay), pk2(0.25f * az, 0.25f * aw));
    }
    __syncthreads();

    // ---- Phase 2: MFMA + SiLU, h in registers; W streamed from L2 ----
    frag_ab a[4];
#pragma unroll
    for (int s = 0; s < 4; ++s)
        a[s] = *(const frag_ab*)(&xs[mA][32 * s + 8 * q]);

    float hv[4][4];
    float ps[4]  = {0.f, 0.f, 0.f, 0.f};
    float pss[4] = {0.f, 0.f, 0.f, 0.f};

#pragma unroll
    for (int t = 0; t < 4; ++t) {
        const int nrow = wave * 64 + t * 16 + mA;
        const unsigned short* wp = Wb + (size_t)nrow * K_ + 8 * q;
        frag_cd acc = {0.f, 0.f, 0.f, 0.f};
#pragma unroll
        for (int s = 0; s < 4; ++s) {
            const frag_ab bfr = *(const frag_ab*)(wp + 32 * s);
            acc = __builtin_amdgcn_mfma_f32_16x16x32_bf16(a[s], bfr, acc, 0, 0, 0);
        }
        const float bn = bias[nrow];
#pragma unroll
        for (int reg = 0; reg < 4; ++reg) {
            const float z = acc[reg] + bn;
            const float h = z / (1.f + __expf(-z));   // silu
            hv[t][reg] = h;
            ps[reg]  += h;
            pss[reg] += h * h;
        }
    }

    // 16-lane butterfly over mA: sums over this wave's 64 cols per token
#pragma unroll
    for (int off = 1; off < 16; off <<= 1) {
#pragma unroll
        for (int reg = 0; reg < 4; ++reg) {
            ps[reg]  += __shfl_xor(ps[reg],  off, 64);
            pss[reg] += __shfl_xor(pss[reg], off, 64);
        }
    }
    if (mA == 0) {
        *(float4*)(&part_s [wave][q * 4]) = make_float4(ps[0],  ps[1],  ps[2],  ps[3]);
        *(float4*)(&part_ss[wave][q * 4]) = make_float4(pss[0], pss[1], pss[2], pss[3]);
    }
    __syncthreads();

    const float4 S0 = *(const float4*)(&part_s [0][q * 4]);
    const float4 S1 = *(const float4*)(&part_s [1][q * 4]);
    const float4 S2 = *(const float4*)(&part_s [2][q * 4]);
    const float4 S3 = *(const float4*)(&part_s [3][q * 4]);
    const float4 T0 = *(const float4*)(&part_ss[0][q * 4]);
    const float4 T1 = *(const float4*)(&part_ss[1][q * 4]);
    const float4 T2 = *(const float4*)(&part_ss[2][q * 4]);
    const float4 T3 = *(const float4*)(&part_ss[3][q * 4]);

    float mu[4], rs[4];
    {
        const float s[4]  = {S0.x + S1.x + S2.x + S3.x, S0.y + S1.y + S2.y + S3.y,
                             S0.z + S1.z + S2.z + S3.z, S0.w + S1.w + S2.w + S3.w};
        const float ss[4] = {T0.x + T1.x + T2.x + T3.x, T0.y + T1.y + T2.y + T3.y,
                             T0.z + T1.z + T2.z + T3.z, T0.w + T1.w + T2.w + T3.w};
#pragma unroll
        for (int reg = 0; reg < 4; ++reg) {
            mu[reg] = s[reg] * (1.f / D_);
            const float var = ss[reg] * (1.f / D_) - mu[reg] * mu[reg];
            rs[reg] = rsqrtf(var + LN_EPS);
        }
    }

    // ---- direct register store ----
    const size_t obase = (size_t)b * (NTOK_ * D_);
#pragma unroll
    for (int t = 0; t < 4; ++t) {
        const int col = wave * 64 + t * 16 + mA;
        const float gm = gamma[col];
        const float bb = beta[col];
        float* op = out + obase + col;
#pragma unroll
        for (int reg = 0; reg < 4; ++reg)
            op[(size_t)(q * 4 + reg) * D_] = (hv[t][reg] - mu[reg]) * rs[reg] * gm + bb;
    }
}

extern "C" void kernel_launch(void* const* d_in, const int* in_sizes, int n_in,
                              void* d_out, int out_size, void* d_ws, size_t ws_size,
                              hipStream_t stream) {
    const int*   int_feats    = (const int*)  d_in[0];
    const int*   missing_mask = (const int*)  d_in[1];
    const int*   group_idx    = (const int*)  d_in[2];
    const float* emb_tables   = (const float*)d_in[3];
    const float* missing_emb  = (const float*)d_in[4];
    const float* W            = (const float*)d_in[5];
    const float* bias         = (const float*)d_in[6];
    const float* gamma        = (const float*)d_in[7];
    const float* beta         = (const float*)d_in[8];
    float* out = (float*)d_out;

    unsigned short* Wb = (unsigned short*)d_ws;   // 64 KB bf16 W
    convert_w_kernel<<<(WB_ELEMS / 2 + 255) / 256, 256, 0, stream>>>(W, (unsigned int*)Wb);

    const size_t need = 2ull * (WB_ELEMS + MB_ELEMS + EB_ELEMS);   // ~16.5 MB
    if (ws_size >= need) {
        unsigned short* Mb = Wb + WB_ELEMS;
        unsigned short* Eb = Mb + MB_ELEMS;
        const int nch = (EB_ELEMS + MB_ELEMS) / 4;
        convert_tbl_kernel<<<(nch + 255) / 256, 256, 0, stream>>>(
            emb_tables, missing_emb, (uint2*)Eb, (uint2*)Mb);
        fused_tokenizer_kernel<true, 6><<<B_, 256, 0, stream>>>(
            int_feats, missing_mask, group_idx, nullptr, nullptr, Eb, Mb,
            Wb, bias, gamma, beta, out);
    } else {
        fused_tokenizer_kernel<false, 4><<<B_, 256, 0, stream>>>(
            int_feats, missing_mask, group_idx, emb_tables, missing_emb, nullptr, nullptr,
            Wb, bias, gamma, beta, out);
    }
}